// Round 3
// baseline (1275.778 us; speedup 1.0000x reference)
//
#include <hip/hip_runtime.h>

typedef unsigned short u16;
using f32x4  = __attribute__((ext_vector_type(4))) float;
using bf16x8 = __attribute__((ext_vector_type(8))) __bf16;

#define Bz   64
#define Nn   197
#define Dd   768
#define Hh   12
#define HDp  64
#define MLPD 3072
#define ROWS (Bz*Nn)        /* 12608 */
#define NM   (Nn*Nn)        /* 38809 */
#define NPAD 224

// fixed region offsets (bytes)
#define OFF_H    0UL            /* hbuf bf16 12608x768 : 19,365,888 */
#define OFF_X1   19365888UL     /* x1   f32  12608x768 : 38,731,776 */
#define OFF_BIA  58097664UL     /* bias f32  12x197x197:  1,862,832 */
#define OFF_WB   59960496UL     /* bf16 weights        : 14,155,776 */
#define OFF_CH   74116272UL     /* chunked region */
// bf16 weight sub-offsets (elements)
#define WQKV_E 0UL              /* 2304x768 = 1,769,472 */
#define WPRJ_E 1769472UL        /* 768x768  =   589,824 */
#define WFC1_E 2359296UL        /* 3072x768 = 2,359,296 */
#define WFC2_E 4718592UL        /* 768x3072 = 2,359,296 */
// per-batch chunk strides (bytes)
#define QKV_B  907776UL         /* 197*2304*2  */
#define P_B    1059072UL        /* 12*197*224*2 */
#define VT_B   344064UL         /* 12*64*224*2  */
#define CHUNK_B 2310912UL

__device__ inline float b2f(u16 v){ unsigned u = ((unsigned)v) << 16; float f; __builtin_memcpy(&f,&u,4); return f; }
__device__ inline u16 f2b(float f){ unsigned u; __builtin_memcpy(&u,&f,4); u += 0x7FFFu + ((u>>16)&1u); return (u16)(u>>16); }

// ---------------- f32 -> bf16 convert (weights staging) ----------------
__global__ __launch_bounds__(256)
void conv_b16(const float* __restrict__ src, u16* __restrict__ dst, int n4)
{
    int t = blockIdx.x*256 + threadIdx.x;
    if (t >= n4) return;
    float4 v = *(const float4*)(src + (size_t)t*4);
    u16* d = dst + (size_t)t*4;
    d[0] = f2b(v.x); d[1] = f2b(v.y); d[2] = f2b(v.z); d[3] = f2b(v.w);
}

// ---------------- generic NT GEMM:  C[M,N] = A[M,K] @ W[N,K]^T ----------------
// EPI: 0=qkv  1=scores  2=pv->y  3=proj->x1(f32)  4=fc1+gelu  5=fc2->out(f32)
template<int EPI>
__global__ __launch_bounds__(256)
void gemm_nt(const u16* __restrict__ A, const u16* __restrict__ W, void* __restrict__ Cp,
             int M, int N, int K, int lda, int ldw, int b0,
             const float* __restrict__ e0, const float* __restrict__ e1,
             const float* __restrict__ e2, const float* __restrict__ e3,
             const float* __restrict__ e4, const float* __restrict__ ef)
{
    const int lane = threadIdx.x & 63;
    const int wave = threadIdx.x >> 6;
    const int z    = blockIdx.z;
    const int m0   = blockIdx.y*256 + wave*64;
    if (m0 >= M) return;
    const int n0   = blockIdx.x*64;
    const int rid  = lane & 15;
    const int kq   = (lane >> 4) * 8;

    const u16* Ab = A;
    const u16* Wb = W;
    if constexpr (EPI == 1) {           // scores: A=q slab, W=k slab inside qkv chunk
        int bb = z/12, hh = z - bb*12;
        Ab = A + ((size_t)bb*Nn)*2304 + hh*64;          // q (already *0.125)
        Wb = W + ((size_t)bb*Nn)*2304 + 768 + hh*64;    // k
    } else if constexpr (EPI == 2) {    // pv: A=P' batch, W=vT batch (chunk-local z)
        Ab = A + (size_t)z*Nn*NPAD;
        Wb = W + (size_t)z*HDp*NPAD;
    }

    f32x4 acc[4][4];
#pragma unroll
    for (int i = 0; i < 4; ++i)
#pragma unroll
        for (int j = 0; j < 4; ++j) acc[i][j] = (f32x4){0.f,0.f,0.f,0.f};

    for (int k0 = 0; k0 < K; k0 += 32) {
        bf16x8 af[4], wf[4];
#pragma unroll
        for (int i = 0; i < 4; ++i) {
            int r = m0 + i*16 + rid; if (r > M-1) r = M-1;
            af[i] = *(const bf16x8*)(Ab + (size_t)r*lda + k0 + kq);
        }
#pragma unroll
        for (int j = 0; j < 4; ++j) {
            int c = n0 + j*16 + rid; if (c > N-1) c = N-1;
            wf[j] = *(const bf16x8*)(Wb + (size_t)c*ldw + k0 + kq);
        }
#pragma unroll
        for (int i = 0; i < 4; ++i)
#pragma unroll
            for (int j = 0; j < 4; ++j)
                acc[i][j] = __builtin_amdgcn_mfma_f32_16x16x32_bf16(af[i], wf[j], acc[i][j], 0, 0, 0);
    }

    const int rq = (lane >> 4) * 4;   // C/D: row = quad*4 + reg, col = lane&15
    const int cc = lane & 15;
#pragma unroll
    for (int i = 0; i < 4; ++i) {
#pragma unroll
        for (int j = 0; j < 4; ++j) {
#pragma unroll
            for (int r = 0; r < 4; ++r) {
                int gm = m0 + i*16 + rq + r;
                int gn = n0 + j*16 + cc;
                if (gm >= M) continue;
                if constexpr (EPI == 1) {
                    // write scores for gn<197, zero the pad cols [197,224)
                    if (gn < NPAD) {
                        u16 st = 0;
                        if (gn < N) {
                            int hh = z - (z/12)*12;
                            float v = acc[i][j][r] + ef[(size_t)hh*NM + gm*Nn + gn];
                            st = f2b(v);
                        }
                        ((u16*)Cp)[(size_t)z*Nn*NPAD + gm*NPAD + gn] = st;
                    }
                    continue;
                }
                if (gn >= N) continue;
                float v = acc[i][j][r];
                if constexpr (EPI == 0) {
                    float bias = 0.f;
                    if (gn < 768) bias = e0[gn];
                    else if (gn >= 1536) bias = e1[gn-1536];
                    v = (v + bias) * e2[gn] + e3[gn];
                    if (gn < 768) v *= 0.125f;          // q * HD^-0.5
                    ((u16*)Cp)[(size_t)gm*2304 + gn] = f2b(v);
                } else if constexpr (EPI == 2) {
                    int bb = z/12, kk = z - (z/12)*12;
                    ((u16*)Cp)[((size_t)(b0+bb)*Nn + gm)*768 + kk*64 + gn] = f2b(v);
                } else if constexpr (EPI == 3) {
                    v = (v + e0[gn]) * e1[gn] + e2[gn];
                    float xv = e4[(size_t)gm*768 + gn];                // x (f32 input)
                    ((float*)Cp)[(size_t)gm*768 + gn] = xv + e3[gn] * v;
                } else if constexpr (EPI == 4) {
                    v += e0[gn];
                    v = 0.5f * v * (1.f + erff(v * 0.70710678118f));   // exact gelu
                    ((u16*)Cp)[(size_t)gm*3072 + gn] = f2b(v);
                } else {
                    v = (v + e0[gn]) * e1[gn] + e2[gn];
                    float xv = ef[(size_t)gm*768 + gn];                // x1 (f32)
                    ((float*)Cp)[(size_t)gm*768 + gn] = xv + e3[gn] * v;
                }
            }
        }
    }
}

// ---------------- LayerNorm + affine + SSF: f32 in -> bf16 staging out ----------------
__global__ __launch_bounds__(256)
void ln_ssf(const float* __restrict__ x, const float* __restrict__ w, const float* __restrict__ bb,
            const float* __restrict__ sc, const float* __restrict__ sh, u16* __restrict__ out)
{
    const int row = blockIdx.x, tid = threadIdx.x;
    const float* xr = x + (size_t)row * 768;
    float v[3], s1 = 0.f, s2 = 0.f;
#pragma unroll
    for (int i = 0; i < 3; ++i) {
        float f = xr[tid + i*256];
        v[i] = f; s1 += f; s2 += f*f;
    }
    for (int o = 32; o > 0; o >>= 1) { s1 += __shfl_xor(s1, o); s2 += __shfl_xor(s2, o); }
    __shared__ float r1[4], r2[4];
    int wv = tid >> 6;
    if ((tid & 63) == 0) { r1[wv] = s1; r2[wv] = s2; }
    __syncthreads();
    s1 = r1[0]+r1[1]+r1[2]+r1[3];
    s2 = r2[0]+r2[1]+r2[2]+r2[3];
    float mean = s1 * (1.f/768.f);
    float var  = s2 * (1.f/768.f) - mean*mean;
    float rstd = rsqrtf(fmaxf(var, 0.f) + 1e-5f);
#pragma unroll
    for (int i = 0; i < 3; ++i) {
        int c = tid + i*256;
        float h = (v[i] - mean) * rstd * w[c] + bb[c];
        h = h * sc[c] + sh[c];
        out[(size_t)row*768 + c] = f2b(h);
    }
}

// ---------------- rel-pos bias gather: biasf[h][n][m] = table[idx[n,m]][h] ----------------
__global__ __launch_bounds__(256)
void bias_gather(const int* __restrict__ idx, const float* __restrict__ table, float* __restrict__ biasf)
{
    int t = blockIdx.x*256 + threadIdx.x;
    if (t >= NM) return;
    int id = idx[t];
#pragma unroll
    for (int h = 0; h < 12; ++h)
        biasf[(size_t)h*NM + t] = table[id*12 + h];
}

// ---------------- per-row softmax over m (197); pad already zero ----------------
__global__ __launch_bounds__(256)
void softmax_rows(u16* __restrict__ P)
{
    int gid  = blockIdx.x*4 + (threadIdx.x >> 6);   // row index within chunk
    int lane = threadIdx.x & 63;
    u16* row = P + (size_t)gid * NPAD;
    float s[4];
#pragma unroll
    for (int j = 0; j < 4; ++j) {
        int m = lane + j*64;
        s[j] = (m < Nn) ? b2f(row[m]) : -1e30f;
    }
    float mx = fmaxf(fmaxf(s[0], s[1]), fmaxf(s[2], s[3]));
    for (int o = 32; o > 0; o >>= 1) mx = fmaxf(mx, __shfl_xor(mx, o));
    float e[4], sum = 0.f;
#pragma unroll
    for (int j = 0; j < 4; ++j) {
        e[j] = __expf(fmaxf(s[j] - mx, -80.f));
        if (lane + j*64 >= Nn) e[j] = 0.f;
        sum += e[j];
    }
    for (int o = 32; o > 0; o >>= 1) sum += __shfl_xor(sum, o);
    float inv = 1.f / sum;
#pragma unroll
    for (int j = 0; j < 4; ++j) {
        int m = lane + j*64;
        if (m < Nn) row[m] = f2b(e[j] * inv);
    }
}

// ---------------- DCF head mixing, in-place on chunk-local P ----------------
__global__ __launch_bounds__(256)
void dcf_mix(u16* __restrict__ P, const float* __restrict__ bases, int nb)
{
    __shared__ float cf[144];
    int tid = threadIdx.x;
    if (tid < 144) {
        int k = tid / 12, h = tid - k*12;
        cf[h*12 + k] = bases[k*12 + h] + (h == k ? 1.f : 0.f);
    }
    __syncthreads();
    size_t t = (size_t)blockIdx.x*256 + tid;
    if (t >= (size_t)nb*NM) return;
    int b = (int)(t / NM); int r = (int)(t - (size_t)b*NM);
    int n = r / Nn; int m = r - n*Nn;
    size_t base = (((size_t)b*12)*Nn + n)*NPAD + m;
    const size_t hs = (size_t)Nn*NPAD;
    float p[12];
#pragma unroll
    for (int h = 0; h < 12; ++h) p[h] = b2f(P[base + h*hs]);
#pragma unroll
    for (int k = 0; k < 12; ++k) {
        float o = 0.f;
#pragma unroll
        for (int h = 0; h < 12; ++h) o += p[h] * cf[h*12 + k];
        P[base + k*hs] = f2b(o);
    }
}

// ---------------- v transpose per chunk-local (b,h): vT[z][d][m(224)] ----------------
__global__ __launch_bounds__(256)
void v_transpose(const u16* __restrict__ qkv, u16* __restrict__ vT)
{
    __shared__ u16 lds[64*198];
    int z = blockIdx.x;
    int bb = z/12, hh = z - bb*12;
    int tid = threadIdx.x;
    const u16* src = qkv + ((size_t)bb*Nn)*2304 + 1536 + hh*64;
    for (int e = tid; e < Nn*64; e += 256) {
        int m = e >> 6, d = e & 63;
        lds[d*198 + m] = src[(size_t)m*2304 + d];
    }
    __syncthreads();
    u16* dst = vT + (size_t)z*64*NPAD;
    for (int e = tid; e < 64*NPAD; e += 256) {
        int d = e / NPAD, m = e - d*NPAD;
        dst[e] = (m < Nn) ? lds[d*198 + m] : (u16)0;
    }
}

extern "C" void kernel_launch(void* const* d_in, const int* in_sizes, int n_in,
                              void* d_out, int out_size, void* d_ws, size_t ws_size,
                              hipStream_t stream)
{
    const float* x       = (const float*)d_in[0];
    const float* w_qkv   = (const float*)d_in[1];
    const float* q_bias  = (const float*)d_in[2];
    const float* v_bias  = (const float*)d_in[3];
    const float* s_qkv   = (const float*)d_in[4];
    const float* sh_qkv  = (const float*)d_in[5];
    const float* rel_tab = (const float*)d_in[6];
    const float* bases   = (const float*)d_in[7];
    const float* w_proj  = (const float*)d_in[8];
    const float* b_proj  = (const float*)d_in[9];
    const float* s_proj  = (const float*)d_in[10];
    const float* sh_proj = (const float*)d_in[11];
    const float* n1w     = (const float*)d_in[12];
    const float* n1b     = (const float*)d_in[13];
    const float* n2w     = (const float*)d_in[14];
    const float* n2b     = (const float*)d_in[15];
    const float* ss1     = (const float*)d_in[16];
    const float* ssh1    = (const float*)d_in[17];
    const float* ss2     = (const float*)d_in[18];
    const float* ssh2    = (const float*)d_in[19];
    const float* w_fc1   = (const float*)d_in[20];
    const float* b_fc1   = (const float*)d_in[21];
    const float* w_fc2   = (const float*)d_in[22];
    const float* b_fc2   = (const float*)d_in[23];
    const float* s_mlp   = (const float*)d_in[24];
    const float* sh_mlp  = (const float*)d_in[25];
    const float* g1      = (const float*)d_in[26];
    const float* g2      = (const float*)d_in[27];
    const int*   relidx  = (const int*)d_in[28];

    char*  ws   = (char*)d_ws;
    u16*   hbuf = (u16*)(ws + OFF_H);
    float* x1   = (float*)(ws + OFF_X1);
    float* bia  = (float*)(ws + OFF_BIA);
    u16*   wb   = (u16*)(ws + OFF_WB);
    float* out  = (float*)d_out;

    u16* wqkvB = wb + WQKV_E;
    u16* wprjB = wb + WPRJ_E;
    u16* wfc1B = wb + WFC1_E;
    u16* wfc2B = wb + WFC2_E;

    // adaptive attention chunking: nb batches per chunk
    int nb = 64;
    while (nb > 1 && OFF_CH + (size_t)nb*CHUNK_B > ws_size) nb >>= 1;
    const int nchunk = 64 / nb;
    u16* qkvC = (u16*)(ws + OFF_CH);
    u16* PC   = (u16*)(ws + OFF_CH + (size_t)nb*QKV_B);
    u16* vTC  = (u16*)(ws + OFF_CH + (size_t)nb*(QKV_B + P_B));

    // 0) weight conversion f32 -> bf16
    conv_b16<<<dim3(1728), dim3(256), 0, stream>>>(w_qkv, wqkvB, 442368);
    conv_b16<<<dim3(576),  dim3(256), 0, stream>>>(w_proj, wprjB, 147456);
    conv_b16<<<dim3(2304), dim3(256), 0, stream>>>(w_fc1, wfc1B, 589824);
    conv_b16<<<dim3(2304), dim3(256), 0, stream>>>(w_fc2, wfc2B, 589824);

    // 1) LN1 + SSF  (full)
    ln_ssf<<<dim3(ROWS), dim3(256), 0, stream>>>(x, n1w, n1b, ss1, ssh1, hbuf);
    // 2) rel-pos bias gather (once)
    bias_gather<<<dim3(152), dim3(256), 0, stream>>>(relidx, rel_tab, bia);

    // 3) attention, chunked over batches
    for (int c = 0; c < nchunk; ++c) {
        const int b0 = c * nb;
        const int nrows = nb * Nn;
        const int gy = (nrows + 255) / 256;
        gemm_nt<0><<<dim3(36, gy, 1), dim3(256), 0, stream>>>(
            hbuf + (size_t)b0*Nn*768, wqkvB, qkvC,
            nrows, 2304, 768, 768, 768, 0, q_bias, v_bias, s_qkv, sh_qkv, nullptr, nullptr);
        v_transpose<<<dim3(nb*12), dim3(256), 0, stream>>>(qkvC, vTC);
        gemm_nt<1><<<dim3(4, 1, nb*12), dim3(256), 0, stream>>>(
            qkvC, qkvC, PC, Nn, Nn, 64, 2304, 2304, 0,
            nullptr, nullptr, nullptr, nullptr, nullptr, bia);
        softmax_rows<<<dim3(nb*591), dim3(256), 0, stream>>>(PC);
        dcf_mix<<<dim3((nb*NM + 255)/256), dim3(256), 0, stream>>>(PC, bases, nb);
        gemm_nt<2><<<dim3(1, 1, nb*12), dim3(256), 0, stream>>>(
            PC, vTC, hbuf, Nn, 64, NPAD, NPAD, NPAD, b0,
            nullptr, nullptr, nullptr, nullptr, nullptr, nullptr);
    }

    // 4) proj + SSF + residual -> x1 (f32, full)
    gemm_nt<3><<<dim3(12, 50, 1), dim3(256), 0, stream>>>(
        hbuf, wprjB, x1, ROWS, 768, 768, 768, 768, 0,
        b_proj, s_proj, sh_proj, g1, x, nullptr);
    // 5) LN2 + SSF (full)
    ln_ssf<<<dim3(ROWS), dim3(256), 0, stream>>>(x1, n2w, n2b, ss2, ssh2, hbuf);

    // 6) MLP, row-chunked into the (dead) attention chunk region
    u16* mlpC = qkvC;
    size_t avail = (ws_size > OFF_CH) ? (ws_size - OFF_CH) : (size_t)CHUNK_B;
    int nrM = (int)(avail / (MLPD * 2));
    if (nrM < 1) nrM = 1;
    if (nrM > ROWS) nrM = ROWS;
    for (int r0 = 0; r0 < ROWS; r0 += nrM) {
        int cr = ROWS - r0; if (cr > nrM) cr = nrM;
        int gy = (cr + 255) / 256;
        gemm_nt<4><<<dim3(48, gy, 1), dim3(256), 0, stream>>>(
            hbuf + (size_t)r0*768, wfc1B, mlpC, cr, 3072, 768, 768, 768, 0,
            b_fc1, nullptr, nullptr, nullptr, nullptr, nullptr);
        gemm_nt<5><<<dim3(12, gy, 1), dim3(256), 0, stream>>>(
            mlpC, wfc2B, out + (size_t)r0*768, cr, 768, 3072, 3072, 3072, 0,
            b_fc2, s_mlp, sh_mlp, g2, nullptr, x1 + (size_t)r0*768);
    }
}

// Round 4
// 909.179 us; speedup vs baseline: 1.4032x; 1.4032x over previous
//
#include <hip/hip_runtime.h>

typedef unsigned short u16;
using f32x4  = __attribute__((ext_vector_type(4))) float;
using bf16x8 = __attribute__((ext_vector_type(8))) __bf16;

#define Bz   64
#define Nn   197
#define Dd   768
#define Hh   12
#define HDp  64
#define MLPD 3072
#define ROWS (Bz*Nn)        /* 12608 */
#define NM   (Nn*Nn)        /* 38809 */
#define NPAD 224

// fixed region offsets (bytes)
#define OFF_H    0UL            /* hbuf bf16 12608x768 : 19,365,888 */
#define OFF_X1   19365888UL     /* x1   f32  12608x768 : 38,731,776 */
#define OFF_BIA  58097664UL     /* bias f32  12x197x197:  1,862,832 */
#define OFF_WB   59960496UL     /* bf16 weights        : 14,155,776 */
#define OFF_CH   74116272UL     /* chunked region */
// bf16 weight sub-offsets (elements)
#define WQKV_E 0UL
#define WPRJ_E 1769472UL
#define WFC1_E 2359296UL
#define WFC2_E 4718592UL
// per-batch chunk strides (bytes)
#define QKV_B  907776UL
#define P_B    1059072UL
#define VT_B   344064UL
#define CHUNK_B 2310912UL

__device__ inline float b2f(u16 v){ unsigned u = ((unsigned)v) << 16; float f; __builtin_memcpy(&f,&u,4); return f; }
__device__ inline u16 f2b(float f){ unsigned u; __builtin_memcpy(&u,&f,4); u += 0x7FFFu + ((u>>16)&1u); return (u16)(u>>16); }

__device__ inline void gload_lds16(const u16* g, u16* l) {
    __builtin_amdgcn_global_load_lds((const __attribute__((address_space(1))) void*)g,
                                     (__attribute__((address_space(3))) void*)l, 16, 0, 0);
}

// ---------------- f32 -> bf16 convert (weights staging) ----------------
__global__ __launch_bounds__(256)
void conv_b16(const float* __restrict__ src, u16* __restrict__ dst, int n4)
{
    int t = blockIdx.x*256 + threadIdx.x;
    if (t >= n4) return;
    float4 v = *(const float4*)(src + (size_t)t*4);
    u16* d = dst + (size_t)t*4;
    d[0] = f2b(v.x); d[1] = f2b(v.y); d[2] = f2b(v.z); d[3] = f2b(v.w);
}

// ======== 128x128 LDS-staged NT GEMM (m97 structure): C[M,N] = A[M,K] @ W[N,K]^T ========
// EPI: 0=qkv  3=proj->x1(f32)  4=fc1+gelu  5=fc2->out(f32)
template<int EPI>
__global__ __launch_bounds__(256)
void gemm128(const u16* __restrict__ A, const u16* __restrict__ W, void* __restrict__ Cp,
             int M, int N, int K, int lda, int ldw,
             const float* __restrict__ e0, const float* __restrict__ e1,
             const float* __restrict__ e2, const float* __restrict__ e3,
             const float* __restrict__ e4, const float* __restrict__ ef)
{
    __shared__ __align__(16) u16 sA[128*32];
    __shared__ __align__(16) u16 sB[128*32];
    const int tid  = threadIdx.x;
    const int lane = tid & 63;
    const int wave = tid >> 6;
    const int wy   = wave >> 1, wx = wave & 1;
    const int m0   = blockIdx.y * 128;
    const int n0   = blockIdx.x * 128;
    const int rid  = lane & 15;
    const int kq   = (lane >> 4) * 8;

    // staging: LDS element offset = pass*2048 + wave*512 + lane*8; row=e>>5, col=e&31
    const int eoff = wave*512 + lane*8;
    const int rT0  = eoff >> 5;            // rows 16*wave .. 16*wave+15
    const int rT1  = (eoff + 2048) >> 5;   // rows 64+16*wave ..
    const int cT   = eoff & 31;
    u16* ldsA0 = sA + wave*512;
    u16* ldsA1 = sA + 2048 + wave*512;
    u16* ldsB0 = sB + wave*512;
    u16* ldsB1 = sB + 2048 + wave*512;

    int ga0 = m0 + rT0; if (ga0 > M-1) ga0 = M-1;
    int ga1 = m0 + rT1; if (ga1 > M-1) ga1 = M-1;
    int gb0 = n0 + rT0; if (gb0 > N-1) gb0 = N-1;
    int gb1 = n0 + rT1; if (gb1 > N-1) gb1 = N-1;
    const u16* Ar0 = A + (size_t)ga0*lda + cT;
    const u16* Ar1 = A + (size_t)ga1*lda + cT;
    const u16* Wr0 = W + (size_t)gb0*ldw + cT;
    const u16* Wr1 = W + (size_t)gb1*ldw + cT;

    f32x4 acc[4][4];
#pragma unroll
    for (int i = 0; i < 4; ++i)
#pragma unroll
        for (int j = 0; j < 4; ++j) acc[i][j] = (f32x4){0.f,0.f,0.f,0.f};

    for (int k0 = 0; k0 < K; k0 += 32) {
        gload_lds16(Ar0 + k0, ldsA0);
        gload_lds16(Ar1 + k0, ldsA1);
        gload_lds16(Wr0 + k0, ldsB0);
        gload_lds16(Wr1 + k0, ldsB1);
        __syncthreads();
        bf16x8 af[4], wf[4];
#pragma unroll
        for (int i = 0; i < 4; ++i)
            af[i] = *(const bf16x8*)(sA + (wy*64 + i*16 + rid)*32 + kq);
#pragma unroll
        for (int j = 0; j < 4; ++j)
            wf[j] = *(const bf16x8*)(sB + (wx*64 + j*16 + rid)*32 + kq);
#pragma unroll
        for (int i = 0; i < 4; ++i)
#pragma unroll
            for (int j = 0; j < 4; ++j)
                acc[i][j] = __builtin_amdgcn_mfma_f32_16x16x32_bf16(af[i], wf[j], acc[i][j], 0, 0, 0);
        __syncthreads();
    }

    const int rq = (lane >> 4) * 4;
    const int cc = lane & 15;
#pragma unroll
    for (int i = 0; i < 4; ++i) {
#pragma unroll
        for (int j = 0; j < 4; ++j) {
#pragma unroll
            for (int r = 0; r < 4; ++r) {
                int gm = m0 + wy*64 + i*16 + rq + r;
                int gn = n0 + wx*64 + j*16 + cc;
                if (gm >= M || gn >= N) continue;
                float v = acc[i][j][r];
                if constexpr (EPI == 0) {
                    float bias = 0.f;
                    if (gn < 768) bias = e0[gn];
                    else if (gn >= 1536) bias = e1[gn-1536];
                    v = (v + bias) * e2[gn] + e3[gn];
                    if (gn < 768) v *= 0.125f;
                    ((u16*)Cp)[(size_t)gm*2304 + gn] = f2b(v);
                } else if constexpr (EPI == 3) {
                    v = (v + e0[gn]) * e1[gn] + e2[gn];
                    float xv = e4[(size_t)gm*768 + gn];
                    ((float*)Cp)[(size_t)gm*768 + gn] = xv + e3[gn] * v;
                } else if constexpr (EPI == 4) {
                    v += e0[gn];
                    v = 0.5f * v * (1.f + erff(v * 0.70710678118f));
                    ((u16*)Cp)[(size_t)gm*3072 + gn] = f2b(v);
                } else {
                    v = (v + e0[gn]) * e1[gn] + e2[gn];
                    float xv = ef[(size_t)gm*768 + gn];
                    ((float*)Cp)[(size_t)gm*768 + gn] = xv + e3[gn] * v;
                }
            }
        }
    }
}

// ======== direct-load NT GEMM for small-K attention GEMMs ========
// EPI: 1=scores  2=pv->y
template<int EPI>
__global__ __launch_bounds__(256)
void gemm_nt(const u16* __restrict__ A, const u16* __restrict__ W, void* __restrict__ Cp,
             int M, int N, int K, int lda, int ldw, int b0,
             const float* __restrict__ ef)
{
    const int lane = threadIdx.x & 63;
    const int wave = threadIdx.x >> 6;
    const int z    = blockIdx.z;
    const int m0   = blockIdx.y*256 + wave*64;
    if (m0 >= M) return;
    const int n0   = blockIdx.x*64;
    const int rid  = lane & 15;
    const int kq   = (lane >> 4) * 8;

    const u16* Ab = A;
    const u16* Wb = W;
    if constexpr (EPI == 1) {
        int bb = z/12, hh = z - bb*12;
        Ab = A + ((size_t)bb*Nn)*2304 + hh*64;          // q (already *0.125)
        Wb = W + ((size_t)bb*Nn)*2304 + 768 + hh*64;    // k
    } else {
        Ab = A + (size_t)z*Nn*NPAD;
        Wb = W + (size_t)z*HDp*NPAD;
    }

    f32x4 acc[4][4];
#pragma unroll
    for (int i = 0; i < 4; ++i)
#pragma unroll
        for (int j = 0; j < 4; ++j) acc[i][j] = (f32x4){0.f,0.f,0.f,0.f};

    for (int k0 = 0; k0 < K; k0 += 32) {
        bf16x8 af[4], wf[4];
#pragma unroll
        for (int i = 0; i < 4; ++i) {
            int r = m0 + i*16 + rid; if (r > M-1) r = M-1;
            af[i] = *(const bf16x8*)(Ab + (size_t)r*lda + k0 + kq);
        }
#pragma unroll
        for (int j = 0; j < 4; ++j) {
            int c = n0 + j*16 + rid; if (c > N-1) c = N-1;
            wf[j] = *(const bf16x8*)(Wb + (size_t)c*ldw + k0 + kq);
        }
#pragma unroll
        for (int i = 0; i < 4; ++i)
#pragma unroll
            for (int j = 0; j < 4; ++j)
                acc[i][j] = __builtin_amdgcn_mfma_f32_16x16x32_bf16(af[i], wf[j], acc[i][j], 0, 0, 0);
    }

    const int rq = (lane >> 4) * 4;
    const int cc = lane & 15;
#pragma unroll
    for (int i = 0; i < 4; ++i) {
#pragma unroll
        for (int j = 0; j < 4; ++j) {
#pragma unroll
            for (int r = 0; r < 4; ++r) {
                int gm = m0 + i*16 + rq + r;
                int gn = n0 + j*16 + cc;
                if (gm >= M) continue;
                if constexpr (EPI == 1) {
                    if (gn < NPAD) {
                        u16 st = 0;
                        if (gn < N) {
                            int hh = z - (z/12)*12;
                            float v = acc[i][j][r] + ef[(size_t)hh*NM + gm*Nn + gn];
                            st = f2b(v);
                        }
                        ((u16*)Cp)[(size_t)z*Nn*NPAD + gm*NPAD + gn] = st;
                    }
                } else {
                    if (gn >= N) continue;
                    int bb = z/12, kk = z - (z/12)*12;
                    ((u16*)Cp)[((size_t)(b0+bb)*Nn + gm)*768 + kk*64 + gn] = f2b(acc[i][j][r]);
                }
            }
        }
    }
}

// ---------------- LayerNorm + affine + SSF: f32 in -> bf16 staging out ----------------
__global__ __launch_bounds__(256)
void ln_ssf(const float* __restrict__ x, const float* __restrict__ w, const float* __restrict__ bb,
            const float* __restrict__ sc, const float* __restrict__ sh, u16* __restrict__ out)
{
    const int row = blockIdx.x, tid = threadIdx.x;
    const float* xr = x + (size_t)row * 768;
    float v[3], s1 = 0.f, s2 = 0.f;
#pragma unroll
    for (int i = 0; i < 3; ++i) {
        float f = xr[tid + i*256];
        v[i] = f; s1 += f; s2 += f*f;
    }
    for (int o = 32; o > 0; o >>= 1) { s1 += __shfl_xor(s1, o); s2 += __shfl_xor(s2, o); }
    __shared__ float r1[4], r2[4];
    int wv = tid >> 6;
    if ((tid & 63) == 0) { r1[wv] = s1; r2[wv] = s2; }
    __syncthreads();
    s1 = r1[0]+r1[1]+r1[2]+r1[3];
    s2 = r2[0]+r2[1]+r2[2]+r2[3];
    float mean = s1 * (1.f/768.f);
    float var  = s2 * (1.f/768.f) - mean*mean;
    float rstd = rsqrtf(fmaxf(var, 0.f) + 1e-5f);
#pragma unroll
    for (int i = 0; i < 3; ++i) {
        int c = tid + i*256;
        float h = (v[i] - mean) * rstd * w[c] + bb[c];
        h = h * sc[c] + sh[c];
        out[(size_t)row*768 + c] = f2b(h);
    }
}

// ---------------- rel-pos bias gather ----------------
__global__ __launch_bounds__(256)
void bias_gather(const int* __restrict__ idx, const float* __restrict__ table, float* __restrict__ biasf)
{
    int t = blockIdx.x*256 + threadIdx.x;
    if (t >= NM) return;
    int id = idx[t];
#pragma unroll
    for (int h = 0; h < 12; ++h)
        biasf[(size_t)h*NM + t] = table[id*12 + h];
}

// ---------------- per-row softmax over m (197); pad already zero ----------------
__global__ __launch_bounds__(256)
void softmax_rows(u16* __restrict__ P)
{
    int gid  = blockIdx.x*4 + (threadIdx.x >> 6);
    int lane = threadIdx.x & 63;
    u16* row = P + (size_t)gid * NPAD;
    float s[4];
#pragma unroll
    for (int j = 0; j < 4; ++j) {
        int m = lane + j*64;
        s[j] = (m < Nn) ? b2f(row[m]) : -1e30f;
    }
    float mx = fmaxf(fmaxf(s[0], s[1]), fmaxf(s[2], s[3]));
    for (int o = 32; o > 0; o >>= 1) mx = fmaxf(mx, __shfl_xor(mx, o));
    float e[4], sum = 0.f;
#pragma unroll
    for (int j = 0; j < 4; ++j) {
        e[j] = __expf(fmaxf(s[j] - mx, -80.f));
        if (lane + j*64 >= Nn) e[j] = 0.f;
        sum += e[j];
    }
    for (int o = 32; o > 0; o >>= 1) sum += __shfl_xor(sum, o);
    float inv = 1.f / sum;
#pragma unroll
    for (int j = 0; j < 4; ++j) {
        int m = lane + j*64;
        if (m < Nn) row[m] = f2b(e[j] * inv);
    }
}

// ---------------- DCF head mixing, in-place on chunk-local P ----------------
__global__ __launch_bounds__(256)
void dcf_mix(u16* __restrict__ P, const float* __restrict__ bases, int nb)
{
    __shared__ float cf[144];
    int tid = threadIdx.x;
    if (tid < 144) {
        int k = tid / 12, h = tid - k*12;
        cf[h*12 + k] = bases[k*12 + h] + (h == k ? 1.f : 0.f);
    }
    __syncthreads();
    size_t t = (size_t)blockIdx.x*256 + tid;
    if (t >= (size_t)nb*NM) return;
    int b = (int)(t / NM); int r = (int)(t - (size_t)b*NM);
    int n = r / Nn; int m = r - n*Nn;
    size_t base = (((size_t)b*12)*Nn + n)*NPAD + m;
    const size_t hs = (size_t)Nn*NPAD;
    float p[12];
#pragma unroll
    for (int h = 0; h < 12; ++h) p[h] = b2f(P[base + h*hs]);
#pragma unroll
    for (int k = 0; k < 12; ++k) {
        float o = 0.f;
#pragma unroll
        for (int h = 0; h < 12; ++h) o += p[h] * cf[h*12 + k];
        P[base + k*hs] = f2b(o);
    }
}

// ---------------- v transpose per chunk-local (b,h) ----------------
__global__ __launch_bounds__(256)
void v_transpose(const u16* __restrict__ qkv, u16* __restrict__ vT)
{
    __shared__ u16 lds[64*198];
    int z = blockIdx.x;
    int bb = z/12, hh = z - bb*12;
    int tid = threadIdx.x;
    const u16* src = qkv + ((size_t)bb*Nn)*2304 + 1536 + hh*64;
    for (int e = tid; e < Nn*64; e += 256) {
        int m = e >> 6, d = e & 63;
        lds[d*198 + m] = src[(size_t)m*2304 + d];
    }
    __syncthreads();
    u16* dst = vT + (size_t)z*64*NPAD;
    for (int e = tid; e < 64*NPAD; e += 256) {
        int d = e / NPAD, m = e - d*NPAD;
        dst[e] = (m < Nn) ? lds[d*198 + m] : (u16)0;
    }
}

extern "C" void kernel_launch(void* const* d_in, const int* in_sizes, int n_in,
                              void* d_out, int out_size, void* d_ws, size_t ws_size,
                              hipStream_t stream)
{
    const float* x       = (const float*)d_in[0];
    const float* w_qkv   = (const float*)d_in[1];
    const float* q_bias  = (const float*)d_in[2];
    const float* v_bias  = (const float*)d_in[3];
    const float* s_qkv   = (const float*)d_in[4];
    const float* sh_qkv  = (const float*)d_in[5];
    const float* rel_tab = (const float*)d_in[6];
    const float* bases   = (const float*)d_in[7];
    const float* w_proj  = (const float*)d_in[8];
    const float* b_proj  = (const float*)d_in[9];
    const float* s_proj  = (const float*)d_in[10];
    const float* sh_proj = (const float*)d_in[11];
    const float* n1w     = (const float*)d_in[12];
    const float* n1b     = (const float*)d_in[13];
    const float* n2w     = (const float*)d_in[14];
    const float* n2b     = (const float*)d_in[15];
    const float* ss1     = (const float*)d_in[16];
    const float* ssh1    = (const float*)d_in[17];
    const float* ss2     = (const float*)d_in[18];
    const float* ssh2    = (const float*)d_in[19];
    const float* w_fc1   = (const float*)d_in[20];
    const float* b_fc1   = (const float*)d_in[21];
    const float* w_fc2   = (const float*)d_in[22];
    const float* b_fc2   = (const float*)d_in[23];
    const float* s_mlp   = (const float*)d_in[24];
    const float* sh_mlp  = (const float*)d_in[25];
    const float* g1      = (const float*)d_in[26];
    const float* g2      = (const float*)d_in[27];
    const int*   relidx  = (const int*)d_in[28];

    char*  ws   = (char*)d_ws;
    u16*   hbuf = (u16*)(ws + OFF_H);
    float* x1   = (float*)(ws + OFF_X1);
    float* bia  = (float*)(ws + OFF_BIA);
    u16*   wb   = (u16*)(ws + OFF_WB);
    float* out  = (float*)d_out;

    u16* wqkvB = wb + WQKV_E;
    u16* wprjB = wb + WPRJ_E;
    u16* wfc1B = wb + WFC1_E;
    u16* wfc2B = wb + WFC2_E;

    int nb = 64;
    while (nb > 1 && OFF_CH + (size_t)nb*CHUNK_B > ws_size) nb >>= 1;
    const int nchunk = 64 / nb;
    u16* qkvC = (u16*)(ws + OFF_CH);
    u16* PC   = (u16*)(ws + OFF_CH + (size_t)nb*QKV_B);
    u16* vTC  = (u16*)(ws + OFF_CH + (size_t)nb*(QKV_B + P_B));

    // 0) weight conversion f32 -> bf16
    conv_b16<<<dim3(1728), dim3(256), 0, stream>>>(w_qkv, wqkvB, 442368);
    conv_b16<<<dim3(576),  dim3(256), 0, stream>>>(w_proj, wprjB, 147456);
    conv_b16<<<dim3(2304), dim3(256), 0, stream>>>(w_fc1, wfc1B, 589824);
    conv_b16<<<dim3(2304), dim3(256), 0, stream>>>(w_fc2, wfc2B, 589824);

    // 1) LN1 + SSF
    ln_ssf<<<dim3(ROWS), dim3(256), 0, stream>>>(x, n1w, n1b, ss1, ssh1, hbuf);
    // 2) rel-pos bias gather
    bias_gather<<<dim3(152), dim3(256), 0, stream>>>(relidx, rel_tab, bia);

    // 3) attention, chunked over batches
    for (int c = 0; c < nchunk; ++c) {
        const int b0 = c * nb;
        const int nrows = nb * Nn;
        const int gy = (nrows + 127) / 128;
        gemm128<0><<<dim3(18, gy), dim3(256), 0, stream>>>(
            hbuf + (size_t)b0*Nn*768, wqkvB, qkvC,
            nrows, 2304, 768, 768, 768, q_bias, v_bias, s_qkv, sh_qkv, nullptr, nullptr);
        v_transpose<<<dim3(nb*12), dim3(256), 0, stream>>>(qkvC, vTC);
        gemm_nt<1><<<dim3(4, 1, nb*12), dim3(256), 0, stream>>>(
            qkvC, qkvC, PC, Nn, Nn, 64, 2304, 2304, 0, bia);
        softmax_rows<<<dim3(nb*591), dim3(256), 0, stream>>>(PC);
        dcf_mix<<<dim3((nb*NM + 255)/256), dim3(256), 0, stream>>>(PC, bases, nb);
        gemm_nt<2><<<dim3(1, 1, nb*12), dim3(256), 0, stream>>>(
            PC, vTC, hbuf, Nn, 64, NPAD, NPAD, NPAD, b0, nullptr);
    }

    // 4) proj + SSF + residual -> x1 (f32)
    gemm128<3><<<dim3(6, 99), dim3(256), 0, stream>>>(
        hbuf, wprjB, x1, ROWS, 768, 768, 768, 768,
        b_proj, s_proj, sh_proj, g1, x, nullptr);
    // 5) LN2 + SSF
    ln_ssf<<<dim3(ROWS), dim3(256), 0, stream>>>(x1, n2w, n2b, ss2, ssh2, hbuf);

    // 6) MLP, row-chunked into the (dead) attention chunk region
    u16* mlpC = qkvC;
    size_t avail = (ws_size > OFF_CH) ? (ws_size - OFF_CH) : (size_t)CHUNK_B;
    int nrM = (int)(avail / (MLPD * 2));
    if (nrM < 1) nrM = 1;
    if (nrM > ROWS) nrM = ROWS;
    for (int r0 = 0; r0 < ROWS; r0 += nrM) {
        int cr = ROWS - r0; if (cr > nrM) cr = nrM;
        int gy = (cr + 127) / 128;
        gemm128<4><<<dim3(24, gy), dim3(256), 0, stream>>>(
            hbuf + (size_t)r0*768, wfc1B, mlpC, cr, 3072, 768, 768, 768,
            b_fc1, nullptr, nullptr, nullptr, nullptr, nullptr);
        gemm128<5><<<dim3(6, gy), dim3(256), 0, stream>>>(
            mlpC, wfc2B, out + (size_t)r0*768, cr, 768, 3072, 3072, 3072,
            b_fc2, s_mlp, sh_mlp, g2, nullptr, x1 + (size_t)r0*768);
    }
}

// Round 5
// 896.702 us; speedup vs baseline: 1.4227x; 1.0139x over previous
//
#include <hip/hip_runtime.h>

typedef unsigned short u16;
using f32x4  = __attribute__((ext_vector_type(4))) float;
using bf16x8 = __attribute__((ext_vector_type(8))) __bf16;

#define Bz   64
#define Nn   197
#define Dd   768
#define Hh   12
#define HDp  64
#define MLPD 3072
#define ROWS (Bz*Nn)        /* 12608 */
#define NM   (Nn*Nn)        /* 38809 */
#define NPAD 224

// fixed region offsets (bytes)
#define OFF_H    0UL            /* hbuf bf16 12608x768 : 19,365,888 */
#define OFF_X1   19365888UL     /* x1   f32  12608x768 : 38,731,776 */
#define OFF_BIA  58097664UL     /* bias f32  12x197x197:  1,862,832 */
#define OFF_WB   59960496UL     /* bf16 weights        : 14,155,776 */
#define OFF_CH   74116272UL     /* chunked region */
// bf16 weight sub-offsets (elements)
#define WQKV_E 0UL
#define WPRJ_E 1769472UL
#define WFC1_E 2359296UL
#define WFC2_E 4718592UL
// per-batch chunk strides (bytes)
#define QKV_B  907776UL
#define P_B    1059072UL
#define VT_B   344064UL
#define CHUNK_B 2310912UL

__device__ inline float b2f(u16 v){ unsigned u = ((unsigned)v) << 16; float f; __builtin_memcpy(&f,&u,4); return f; }
__device__ inline u16 f2b(float f){ unsigned u; __builtin_memcpy(&u,&f,4); u += 0x7FFFu + ((u>>16)&1u); return (u16)(u>>16); }

__device__ inline void gload_lds16(const u16* g, u16* l) {
    __builtin_amdgcn_global_load_lds((const __attribute__((address_space(1))) void*)g,
                                     (__attribute__((address_space(3))) void*)l, 16, 0, 0);
}

// ---------------- f32 -> bf16 convert (weights staging) ----------------
__global__ __launch_bounds__(256)
void conv_b16(const float* __restrict__ src, u16* __restrict__ dst, int n4)
{
    int t = blockIdx.x*256 + threadIdx.x;
    if (t >= n4) return;
    float4 v = *(const float4*)(src + (size_t)t*4);
    u16* d = dst + (size_t)t*4;
    d[0] = f2b(v.x); d[1] = f2b(v.y); d[2] = f2b(v.z); d[3] = f2b(v.w);
}

// ======== 128x128 LDS double-buffered NT GEMM, XOR-swizzled LDS layout ========
// LDS slot for (row r, colblock c of 8 elems): r*32 + (c ^ ((r>>1)&3))*8
// EPI: 0=qkv  3=proj->x1(f32)  4=fc1+gelu  5=fc2->out(f32)
template<int EPI>
__global__ __launch_bounds__(256)
void gemm128(const u16* __restrict__ A, const u16* __restrict__ W, void* __restrict__ Cp,
             int M, int N, int K, int lda, int ldw,
             const float* __restrict__ e0, const float* __restrict__ e1,
             const float* __restrict__ e2, const float* __restrict__ e3,
             const float* __restrict__ e4, const float* __restrict__ ef)
{
    __shared__ __align__(16) u16 sA[2][128*32];
    __shared__ __align__(16) u16 sB[2][128*32];
    const int tid  = threadIdx.x;
    const int lane = tid & 63;
    const int wave = tid >> 6;
    const int wy   = wave >> 1, wx = wave & 1;
    const int m0   = blockIdx.y * 128;
    const int n0   = blockIdx.x * 128;
    const int rid  = lane & 15;
    const int kqb  = lane >> 4;            // colblock 0..3 for fragment reads

    // staging: lane writes LDS slot eoff (pass0) / eoff+2048 (pass1)
    const int eoff = wave*512 + lane*8;
    const int rT0  = eoff >> 5;
    const int rT1  = (eoff + 2048) >> 5;
    const int cs   = (eoff & 31) >> 3;                 // destination colblock slot
    const int c0   = ((cs ^ ((rT0 >> 1) & 3)) << 3);   // source col for pass 0
    const int c1   = ((cs ^ ((rT1 >> 1) & 3)) << 3);   // source col for pass 1

    int ga0 = m0 + rT0; if (ga0 > M-1) ga0 = M-1;
    int ga1 = m0 + rT1; if (ga1 > M-1) ga1 = M-1;
    int gb0 = n0 + rT0; if (gb0 > N-1) gb0 = N-1;
    int gb1 = n0 + rT1; if (gb1 > N-1) gb1 = N-1;
    const u16* Ar0 = A + (size_t)ga0*lda + c0;
    const u16* Ar1 = A + (size_t)ga1*lda + c1;
    const u16* Wr0 = W + (size_t)gb0*ldw + c0;
    const u16* Wr1 = W + (size_t)gb1*ldw + c1;
    const int ldsW = wave*512;

    f32x4 acc[4][4];
#pragma unroll
    for (int i = 0; i < 4; ++i)
#pragma unroll
        for (int j = 0; j < 4; ++j) acc[i][j] = (f32x4){0.f,0.f,0.f,0.f};

    // prologue: stage k0=0 into buffer 0
    gload_lds16(Ar0, sA[0] + ldsW);
    gload_lds16(Ar1, sA[0] + 2048 + ldsW);
    gload_lds16(Wr0, sB[0] + ldsW);
    gload_lds16(Wr1, sB[0] + 2048 + ldsW);
    __syncthreads();

    int buf = 0;
    for (int k0 = 0; k0 < K; k0 += 32, buf ^= 1) {
        if (k0 + 32 < K) {       // prefetch next tile into buf^1
            gload_lds16(Ar0 + k0 + 32, sA[buf^1] + ldsW);
            gload_lds16(Ar1 + k0 + 32, sA[buf^1] + 2048 + ldsW);
            gload_lds16(Wr0 + k0 + 32, sB[buf^1] + ldsW);
            gload_lds16(Wr1 + k0 + 32, sB[buf^1] + 2048 + ldsW);
        }
        bf16x8 af[4], wf[4];
#pragma unroll
        for (int i = 0; i < 4; ++i) {
            int R = wy*64 + i*16 + rid;
            af[i] = *(const bf16x8*)(sA[buf] + R*32 + ((kqb ^ ((R>>1)&3))<<3));
        }
#pragma unroll
        for (int j = 0; j < 4; ++j) {
            int R = wx*64 + j*16 + rid;
            wf[j] = *(const bf16x8*)(sB[buf] + R*32 + ((kqb ^ ((R>>1)&3))<<3));
        }
#pragma unroll
        for (int i = 0; i < 4; ++i)
#pragma unroll
            for (int j = 0; j < 4; ++j)
                acc[i][j] = __builtin_amdgcn_mfma_f32_16x16x32_bf16(af[i], wf[j], acc[i][j], 0, 0, 0);
        __syncthreads();         // drains prefetch, guards buffer reuse
    }

    const int rq = (lane >> 4) * 4;
    const int cc = lane & 15;
#pragma unroll
    for (int i = 0; i < 4; ++i) {
#pragma unroll
        for (int j = 0; j < 4; ++j) {
#pragma unroll
            for (int r = 0; r < 4; ++r) {
                int gm = m0 + wy*64 + i*16 + rq + r;
                int gn = n0 + wx*64 + j*16 + cc;
                if (gm >= M || gn >= N) continue;
                float v = acc[i][j][r];
                if constexpr (EPI == 0) {
                    float bias = 0.f;
                    if (gn < 768) bias = e0[gn];
                    else if (gn >= 1536) bias = e1[gn-1536];
                    v = (v + bias) * e2[gn] + e3[gn];
                    if (gn < 768) v *= 0.125f;
                    ((u16*)Cp)[(size_t)gm*2304 + gn] = f2b(v);
                } else if constexpr (EPI == 3) {
                    v = (v + e0[gn]) * e1[gn] + e2[gn];
                    float xv = e4[(size_t)gm*768 + gn];
                    ((float*)Cp)[(size_t)gm*768 + gn] = xv + e3[gn] * v;
                } else if constexpr (EPI == 4) {
                    v += e0[gn];
                    v = 0.5f * v * (1.f + erff(v * 0.70710678118f));
                    ((u16*)Cp)[(size_t)gm*3072 + gn] = f2b(v);
                } else {
                    v = (v + e0[gn]) * e1[gn] + e2[gn];
                    float xv = ef[(size_t)gm*768 + gn];
                    ((float*)Cp)[(size_t)gm*768 + gn] = xv + e3[gn] * v;
                }
            }
        }
    }
}

// ======== direct-load NT GEMM for small-K attention GEMMs ========
// EPI: 1=scores  2=pv->y
template<int EPI>
__global__ __launch_bounds__(256)
void gemm_nt(const u16* __restrict__ A, const u16* __restrict__ W, void* __restrict__ Cp,
             int M, int N, int K, int lda, int ldw, int b0,
             const float* __restrict__ ef)
{
    const int lane = threadIdx.x & 63;
    const int wave = threadIdx.x >> 6;
    const int z    = blockIdx.z;
    const int m0   = blockIdx.y*256 + wave*64;
    if (m0 >= M) return;
    const int n0   = blockIdx.x*64;
    const int rid  = lane & 15;
    const int kq   = (lane >> 4) * 8;

    const u16* Ab = A;
    const u16* Wb = W;
    if constexpr (EPI == 1) {
        int bb = z/12, hh = z - bb*12;
        Ab = A + ((size_t)bb*Nn)*2304 + hh*64;          // q (already *0.125)
        Wb = W + ((size_t)bb*Nn)*2304 + 768 + hh*64;    // k
    } else {
        Ab = A + (size_t)z*Nn*NPAD;
        Wb = W + (size_t)z*HDp*NPAD;
    }

    f32x4 acc[4][4];
#pragma unroll
    for (int i = 0; i < 4; ++i)
#pragma unroll
        for (int j = 0; j < 4; ++j) acc[i][j] = (f32x4){0.f,0.f,0.f,0.f};

    for (int k0 = 0; k0 < K; k0 += 32) {
        bf16x8 af[4], wf[4];
#pragma unroll
        for (int i = 0; i < 4; ++i) {
            int r = m0 + i*16 + rid; if (r > M-1) r = M-1;
            af[i] = *(const bf16x8*)(Ab + (size_t)r*lda + k0 + kq);
        }
#pragma unroll
        for (int j = 0; j < 4; ++j) {
            int c = n0 + j*16 + rid; if (c > N-1) c = N-1;
            wf[j] = *(const bf16x8*)(Wb + (size_t)c*ldw + k0 + kq);
        }
#pragma unroll
        for (int i = 0; i < 4; ++i)
#pragma unroll
            for (int j = 0; j < 4; ++j)
                acc[i][j] = __builtin_amdgcn_mfma_f32_16x16x32_bf16(af[i], wf[j], acc[i][j], 0, 0, 0);
    }

    const int rq = (lane >> 4) * 4;
    const int cc = lane & 15;
#pragma unroll
    for (int i = 0; i < 4; ++i) {
#pragma unroll
        for (int j = 0; j < 4; ++j) {
#pragma unroll
            for (int r = 0; r < 4; ++r) {
                int gm = m0 + i*16 + rq + r;
                int gn = n0 + j*16 + cc;
                if (gm >= M) continue;
                if constexpr (EPI == 1) {
                    if (gn < NPAD) {
                        u16 st = 0;
                        if (gn < N) {
                            int hh = z - (z/12)*12;
                            float v = acc[i][j][r] + ef[(size_t)hh*NM + gm*Nn + gn];
                            st = f2b(v);
                        }
                        ((u16*)Cp)[(size_t)z*Nn*NPAD + gm*NPAD + gn] = st;
                    }
                } else {
                    if (gn >= N) continue;
                    int bb = z/12, kk = z - (z/12)*12;
                    ((u16*)Cp)[((size_t)(b0+bb)*Nn + gm)*768 + kk*64 + gn] = f2b(acc[i][j][r]);
                }
            }
        }
    }
}

// ---------------- LayerNorm + affine + SSF: f32 in -> bf16 staging out ----------------
__global__ __launch_bounds__(256)
void ln_ssf(const float* __restrict__ x, const float* __restrict__ w, const float* __restrict__ bb,
            const float* __restrict__ sc, const float* __restrict__ sh, u16* __restrict__ out)
{
    const int row = blockIdx.x, tid = threadIdx.x;
    const float* xr = x + (size_t)row * 768;
    float v[3], s1 = 0.f, s2 = 0.f;
#pragma unroll
    for (int i = 0; i < 3; ++i) {
        float f = xr[tid + i*256];
        v[i] = f; s1 += f; s2 += f*f;
    }
    for (int o = 32; o > 0; o >>= 1) { s1 += __shfl_xor(s1, o); s2 += __shfl_xor(s2, o); }
    __shared__ float r1[4], r2[4];
    int wv = tid >> 6;
    if ((tid & 63) == 0) { r1[wv] = s1; r2[wv] = s2; }
    __syncthreads();
    s1 = r1[0]+r1[1]+r1[2]+r1[3];
    s2 = r2[0]+r2[1]+r2[2]+r2[3];
    float mean = s1 * (1.f/768.f);
    float var  = s2 * (1.f/768.f) - mean*mean;
    float rstd = rsqrtf(fmaxf(var, 0.f) + 1e-5f);
#pragma unroll
    for (int i = 0; i < 3; ++i) {
        int c = tid + i*256;
        float h = (v[i] - mean) * rstd * w[c] + bb[c];
        h = h * sc[c] + sh[c];
        out[(size_t)row*768 + c] = f2b(h);
    }
}

// ---------------- rel-pos bias gather ----------------
__global__ __launch_bounds__(256)
void bias_gather(const int* __restrict__ idx, const float* __restrict__ table, float* __restrict__ biasf)
{
    int t = blockIdx.x*256 + threadIdx.x;
    if (t >= NM) return;
    int id = idx[t];
#pragma unroll
    for (int h = 0; h < 12; ++h)
        biasf[(size_t)h*NM + t] = table[id*12 + h];
}

// ---------------- per-row softmax over m (197); pad already zero ----------------
__global__ __launch_bounds__(256)
void softmax_rows(u16* __restrict__ P)
{
    int gid  = blockIdx.x*4 + (threadIdx.x >> 6);
    int lane = threadIdx.x & 63;
    u16* row = P + (size_t)gid * NPAD;
    float s[4];
#pragma unroll
    for (int j = 0; j < 4; ++j) {
        int m = lane + j*64;
        s[j] = (m < Nn) ? b2f(row[m]) : -1e30f;
    }
    float mx = fmaxf(fmaxf(s[0], s[1]), fmaxf(s[2], s[3]));
    for (int o = 32; o > 0; o >>= 1) mx = fmaxf(mx, __shfl_xor(mx, o));
    float e[4], sum = 0.f;
#pragma unroll
    for (int j = 0; j < 4; ++j) {
        e[j] = __expf(fmaxf(s[j] - mx, -80.f));
        if (lane + j*64 >= Nn) e[j] = 0.f;
        sum += e[j];
    }
    for (int o = 32; o > 0; o >>= 1) sum += __shfl_xor(sum, o);
    float inv = 1.f / sum;
#pragma unroll
    for (int j = 0; j < 4; ++j) {
        int m = lane + j*64;
        if (m < Nn) row[m] = f2b(e[j] * inv);
    }
}

// ---------------- DCF head mixing, in-place on chunk-local P ----------------
__global__ __launch_bounds__(256)
void dcf_mix(u16* __restrict__ P, const float* __restrict__ bases, int nb)
{
    __shared__ float cf[144];
    int tid = threadIdx.x;
    if (tid < 144) {
        int k = tid / 12, h = tid - k*12;
        cf[h*12 + k] = bases[k*12 + h] + (h == k ? 1.f : 0.f);
    }
    __syncthreads();
    size_t t = (size_t)blockIdx.x*256 + tid;
    if (t >= (size_t)nb*NM) return;
    int b = (int)(t / NM); int r = (int)(t - (size_t)b*NM);
    int n = r / Nn; int m = r - n*Nn;
    size_t base = (((size_t)b*12)*Nn + n)*NPAD + m;
    const size_t hs = (size_t)Nn*NPAD;
    float p[12];
#pragma unroll
    for (int h = 0; h < 12; ++h) p[h] = b2f(P[base + h*hs]);
#pragma unroll
    for (int k = 0; k < 12; ++k) {
        float o = 0.f;
#pragma unroll
        for (int h = 0; h < 12; ++h) o += p[h] * cf[h*12 + k];
        P[base + k*hs] = f2b(o);
    }
}

// ---------------- v transpose per chunk-local (b,h) ----------------
__global__ __launch_bounds__(256)
void v_transpose(const u16* __restrict__ qkv, u16* __restrict__ vT)
{
    __shared__ u16 lds[64*198];
    int z = blockIdx.x;
    int bb = z/12, hh = z - bb*12;
    int tid = threadIdx.x;
    const u16* src = qkv + ((size_t)bb*Nn)*2304 + 1536 + hh*64;
    for (int e = tid; e < Nn*64; e += 256) {
        int m = e >> 6, d = e & 63;
        lds[d*198 + m] = src[(size_t)m*2304 + d];
    }
    __syncthreads();
    u16* dst = vT + (size_t)z*64*NPAD;
    for (int e = tid; e < 64*NPAD; e += 256) {
        int d = e / NPAD, m = e - d*NPAD;
        dst[e] = (m < Nn) ? lds[d*198 + m] : (u16)0;
    }
}

extern "C" void kernel_launch(void* const* d_in, const int* in_sizes, int n_in,
                              void* d_out, int out_size, void* d_ws, size_t ws_size,
                              hipStream_t stream)
{
    const float* x       = (const float*)d_in[0];
    const float* w_qkv   = (const float*)d_in[1];
    const float* q_bias  = (const float*)d_in[2];
    const float* v_bias  = (const float*)d_in[3];
    const float* s_qkv   = (const float*)d_in[4];
    const float* sh_qkv  = (const float*)d_in[5];
    const float* rel_tab = (const float*)d_in[6];
    const float* bases   = (const float*)d_in[7];
    const float* w_proj  = (const float*)d_in[8];
    const float* b_proj  = (const float*)d_in[9];
    const float* s_proj  = (const float*)d_in[10];
    const float* sh_proj = (const float*)d_in[11];
    const float* n1w     = (const float*)d_in[12];
    const float* n1b     = (const float*)d_in[13];
    const float* n2w     = (const float*)d_in[14];
    const float* n2b     = (const float*)d_in[15];
    const float* ss1     = (const float*)d_in[16];
    const float* ssh1    = (const float*)d_in[17];
    const float* ss2     = (const float*)d_in[18];
    const float* ssh2    = (const float*)d_in[19];
    const float* w_fc1   = (const float*)d_in[20];
    const float* b_fc1   = (const float*)d_in[21];
    const float* w_fc2   = (const float*)d_in[22];
    const float* b_fc2   = (const float*)d_in[23];
    const float* s_mlp   = (const float*)d_in[24];
    const float* sh_mlp  = (const float*)d_in[25];
    const float* g1      = (const float*)d_in[26];
    const float* g2      = (const float*)d_in[27];
    const int*   relidx  = (const int*)d_in[28];

    char*  ws   = (char*)d_ws;
    u16*   hbuf = (u16*)(ws + OFF_H);
    float* x1   = (float*)(ws + OFF_X1);
    float* bia  = (float*)(ws + OFF_BIA);
    u16*   wb   = (u16*)(ws + OFF_WB);
    float* out  = (float*)d_out;

    u16* wqkvB = wb + WQKV_E;
    u16* wprjB = wb + WPRJ_E;
    u16* wfc1B = wb + WFC1_E;
    u16* wfc2B = wb + WFC2_E;

    int nb = 64;
    while (nb > 1 && OFF_CH + (size_t)nb*CHUNK_B > ws_size) nb >>= 1;
    const int nchunk = 64 / nb;
    u16* qkvC = (u16*)(ws + OFF_CH);
    u16* PC   = (u16*)(ws + OFF_CH + (size_t)nb*QKV_B);
    u16* vTC  = (u16*)(ws + OFF_CH + (size_t)nb*(QKV_B + P_B));

    // 0) weight conversion f32 -> bf16
    conv_b16<<<dim3(1728), dim3(256), 0, stream>>>(w_qkv, wqkvB, 442368);
    conv_b16<<<dim3(576),  dim3(256), 0, stream>>>(w_proj, wprjB, 147456);
    conv_b16<<<dim3(2304), dim3(256), 0, stream>>>(w_fc1, wfc1B, 589824);
    conv_b16<<<dim3(2304), dim3(256), 0, stream>>>(w_fc2, wfc2B, 589824);

    // 1) LN1 + SSF
    ln_ssf<<<dim3(ROWS), dim3(256), 0, stream>>>(x, n1w, n1b, ss1, ssh1, hbuf);
    // 2) rel-pos bias gather
    bias_gather<<<dim3(152), dim3(256), 0, stream>>>(relidx, rel_tab, bia);

    // 3) attention, chunked over batches
    for (int c = 0; c < nchunk; ++c) {
        const int b0 = c * nb;
        const int nrows = nb * Nn;
        const int gy = (nrows + 127) / 128;
        gemm128<0><<<dim3(18, gy), dim3(256), 0, stream>>>(
            hbuf + (size_t)b0*Nn*768, wqkvB, qkvC,
            nrows, 2304, 768, 768, 768, q_bias, v_bias, s_qkv, sh_qkv, nullptr, nullptr);
        v_transpose<<<dim3(nb*12), dim3(256), 0, stream>>>(qkvC, vTC);
        gemm_nt<1><<<dim3(4, 1, nb*12), dim3(256), 0, stream>>>(
            qkvC, qkvC, PC, Nn, Nn, 64, 2304, 2304, 0, bia);
        softmax_rows<<<dim3(nb*591), dim3(256), 0, stream>>>(PC);
        dcf_mix<<<dim3((nb*NM + 255)/256), dim3(256), 0, stream>>>(PC, bases, nb);
        gemm_nt<2><<<dim3(1, 1, nb*12), dim3(256), 0, stream>>>(
            PC, vTC, hbuf, Nn, 64, NPAD, NPAD, NPAD, b0, nullptr);
    }

    // 4) proj + SSF + residual -> x1 (f32)
    gemm128<3><<<dim3(6, 99), dim3(256), 0, stream>>>(
        hbuf, wprjB, x1, ROWS, 768, 768, 768, 768,
        b_proj, s_proj, sh_proj, g1, x, nullptr);
    // 5) LN2 + SSF
    ln_ssf<<<dim3(ROWS), dim3(256), 0, stream>>>(x1, n2w, n2b, ss2, ssh2, hbuf);

    // 6) MLP, row-chunked into the (dead) attention chunk region
    u16* mlpC = qkvC;
    size_t avail = (ws_size > OFF_CH) ? (ws_size - OFF_CH) : (size_t)CHUNK_B;
    int nrM = (int)(avail / (MLPD * 2));
    if (nrM < 1) nrM = 1;
    if (nrM > ROWS) nrM = ROWS;
    for (int r0 = 0; r0 < ROWS; r0 += nrM) {
        int cr = ROWS - r0; if (cr > nrM) cr = nrM;
        int gy = (cr + 127) / 128;
        gemm128<4><<<dim3(24, gy), dim3(256), 0, stream>>>(
            hbuf + (size_t)r0*768, wfc1B, mlpC, cr, 3072, 768, 768, 768,
            b_fc1, nullptr, nullptr, nullptr, nullptr, nullptr);
        gemm128<5><<<dim3(6, gy), dim3(256), 0, stream>>>(
            mlpC, wfc2B, out + (size_t)r0*768, cr, 768, 3072, 3072, 3072,
            b_fc2, s_mlp, sh_mlp, g2, nullptr, x1 + (size_t)r0*768);
    }
}